// Round 1
// baseline (548.215 us; speedup 1.0000x reference)
//
#include <hip/hip_runtime.h>

// Problem constants (fixed by setup_inputs): B=1024, T=200, D=128, H=128
#define B_SZ 1024
#define T_SZ 200
#define D_SZ 128
#define H_SZ 128

typedef __attribute__((ext_vector_type(8))) short    bf16x8;
typedef __attribute__((ext_vector_type(4))) float    f32x4;
typedef __attribute__((ext_vector_type(4))) int      i32x4;
typedef __attribute__((ext_vector_type(2))) unsigned u32x2;

__device__ __forceinline__ unsigned short f2bf(float f) {
  // round-to-nearest-even bf16 (inputs finite)
  unsigned u = __builtin_bit_cast(unsigned, f);
  u += 0x7fffu + ((u >> 16) & 1u);
  return (unsigned short)(u >> 16);
}
__device__ __forceinline__ float bf2f(unsigned us) {
  unsigned v = us << 16;
  return __builtin_bit_cast(float, v);
}
__device__ __forceinline__ float sigmoid_fast(float x) {
  float e = __builtin_amdgcn_exp2f(-1.442695041f * x);
  return __builtin_amdgcn_rcpf(1.0f + e);
}
__device__ __forceinline__ float tanh_fast(float x) {
  // tanh(x) = 1 - 2/(exp(2x)+1); saturates correctly via inf/0
  float e = __builtin_amdgcn_exp2f(2.885390082f * x);
  return 1.0f - 2.0f * __builtin_amdgcn_rcpf(e + 1.0f);
}

// ---------------------------------------------------------------------------
// Kernel 1: XGC[bt][t][col(384)][row(16)] (bf16) = x @ Wx + bias
//   cols 0..255  : x @ W_gate[0:128,:] + b_gate
//   cols 256..383: x @ W_cand[0:128,:] + b_cand
// Blocked layout matches kernel 2's MFMA C-layout (col = lane&15, rows = quad*4+i),
// so lane stores/loads are contiguous dwordx2 and each wave-instr covers 512 B.
// ---------------------------------------------------------------------------
__global__ __launch_bounds__(256, 2) void xproj_kernel(
    const float* __restrict__ X,   // [B,T,D]
    const float* __restrict__ Wg,  // [256,256]
    const float* __restrict__ bg,  // [256]
    const float* __restrict__ Wc,  // [256,128]
    const float* __restrict__ bc,  // [128]
    unsigned short* __restrict__ XGC)
{
  const int tid  = threadIdx.x;
  const int lane = tid & 63;
  const int wave = tid >> 6;   // 0..3
  const int m16  = lane & 15;
  const int q    = lane >> 4;  // 0..3

  // B-fragments in registers, loaded once per workgroup.
  bf16x8 wgf[4][4];  // gate: wave owns cols [64*wave, 64*wave+64)
  bf16x8 wcf[2][4];  // cand: wave owns cols [32*wave, 32*wave+32)
  float  gbias[4], cbias[2];
  #pragma unroll
  for (int nt = 0; nt < 4; ++nt) {
    int col = wave * 64 + nt * 16 + m16;
    gbias[nt] = bg[col];
    #pragma unroll
    for (int kb = 0; kb < 4; ++kb) {
      bf16x8 f;
      #pragma unroll
      for (int j = 0; j < 8; ++j) {
        int k = kb * 32 + q * 8 + j;          // x-part rows 0..127
        f[j] = (short)f2bf(Wg[(size_t)k * 256 + col]);
      }
      wgf[nt][kb] = f;
    }
  }
  #pragma unroll
  for (int nt = 0; nt < 2; ++nt) {
    int col = wave * 32 + nt * 16 + m16;
    cbias[nt] = bc[col];
    #pragma unroll
    for (int kb = 0; kb < 4; ++kb) {
      bf16x8 f;
      #pragma unroll
      for (int j = 0; j < 8; ++j) {
        int k = kb * 32 + q * 8 + j;
        f[j] = (short)f2bf(Wc[(size_t)k * 128 + col]);
      }
      wcf[nt][kb] = f;
    }
  }

  // 64 b_tiles x 200 t = 12800 tiles; 25 per workgroup (512 wgs).
  const int t0 = blockIdx.x * 25;
  for (int it = 0; it < 25; ++it) {
    int tile = t0 + it;
    int bt   = tile / 200;
    int t    = tile % 200;

    // A-fragments from global: lane m16 = batch row within tile.
    int b = bt * 16 + m16;
    const float* xrow = X + (size_t)(b * T_SZ + t) * D_SZ;
    bf16x8 af[4];
    #pragma unroll
    for (int kb = 0; kb < 4; ++kb) {
      f32x4 x0 = *(const f32x4*)(xrow + kb * 32 + q * 8);
      f32x4 x1 = *(const f32x4*)(xrow + kb * 32 + q * 8 + 4);
      bf16x8 f;
      f[0]=(short)f2bf(x0.x); f[1]=(short)f2bf(x0.y); f[2]=(short)f2bf(x0.z); f[3]=(short)f2bf(x0.w);
      f[4]=(short)f2bf(x1.x); f[5]=(short)f2bf(x1.y); f[6]=(short)f2bf(x1.z); f[7]=(short)f2bf(x1.w);
      af[kb] = f;
    }

    unsigned short* outbase = XGC + ((size_t)bt * 200 + t) * 384 * 16;
    #pragma unroll
    for (int nt = 0; nt < 4; ++nt) {
      f32x4 acc = { gbias[nt], gbias[nt], gbias[nt], gbias[nt] };
      #pragma unroll
      for (int kb = 0; kb < 4; ++kb)
        acc = __builtin_amdgcn_mfma_f32_16x16x32_bf16(af[kb], wgf[nt][kb], acc, 0, 0, 0);
      int col = wave * 64 + nt * 16 + m16;
      unsigned h0=f2bf(acc[0]), h1=f2bf(acc[1]), h2=f2bf(acc[2]), h3=f2bf(acc[3]);
      u32x2 pk = { h0 | (h1 << 16), h2 | (h3 << 16) };
      *(u32x2*)(outbase + col * 16 + q * 4) = pk;
    }
    #pragma unroll
    for (int nt = 0; nt < 2; ++nt) {
      f32x4 acc = { cbias[nt], cbias[nt], cbias[nt], cbias[nt] };
      #pragma unroll
      for (int kb = 0; kb < 4; ++kb)
        acc = __builtin_amdgcn_mfma_f32_16x16x32_bf16(af[kb], wcf[nt][kb], acc, 0, 0, 0);
      int col = 256 + wave * 32 + nt * 16 + m16;
      unsigned h0=f2bf(acc[0]), h1=f2bf(acc[1]), h2=f2bf(acc[2]), h3=f2bf(acc[3]);
      u32x2 pk = { h0 | (h1 << 16), h2 | (h3 << 16) };
      *(u32x2*)(outbase + col * 16 + q * 4) = pk;
    }
  }
}

// ---------------------------------------------------------------------------
// Kernel 2: GRU recurrence. 64 wgs x 16 batch rows, 4 waves.
//   wave w: gate cols [64w,64w+64) (w<2 -> r, w>=2 -> u); h/cand cols [32w,32w+32)
// Recurrent weights in VGPR B-frags, h in fp32 regs, LDS only for exchange.
// ---------------------------------------------------------------------------
__global__ __launch_bounds__(256, 1) void gru_kernel(
    const unsigned short* __restrict__ XGC,
    const int*   __restrict__ seq_len,
    const float* __restrict__ Wg,   // [256,256] rows 128.. = h-part
    const float* __restrict__ Wc,   // [256,128] rows 128.. = h-part
    float* __restrict__ Y)          // [B,T,H]
{
  __shared__ unsigned short hA[16 * 136];   // h bf16, A-layout [m][k], pad 128->136
  __shared__ unsigned short rhA[16 * 136];  // r*h bf16, A-layout
  __shared__ float rbuf[128 * 20];          // r fp32, [col][row], pad 16->20
  __shared__ float ubuf[128 * 20];          // u fp32, [col][row]

  const int tid  = threadIdx.x;
  const int lane = tid & 63;
  const int wave = tid >> 6;
  const int m16  = lane & 15;
  const int q    = lane >> 4;

  // Recurrent-weight B-fragments (h-part rows 128..255).
  bf16x8 wgf[4][4], wcf[2][4];
  #pragma unroll
  for (int nt = 0; nt < 4; ++nt)
    #pragma unroll
    for (int kb = 0; kb < 4; ++kb) {
      bf16x8 f;
      #pragma unroll
      for (int j = 0; j < 8; ++j) {
        int k = kb * 32 + q * 8 + j;
        f[j] = (short)f2bf(Wg[(size_t)(128 + k) * 256 + wave * 64 + nt * 16 + m16]);
      }
      wgf[nt][kb] = f;
    }
  #pragma unroll
  for (int nt = 0; nt < 2; ++nt)
    #pragma unroll
    for (int kb = 0; kb < 4; ++kb) {
      bf16x8 f;
      #pragma unroll
      for (int j = 0; j < 8; ++j) {
        int k = kb * 32 + q * 8 + j;
        f[j] = (short)f2bf(Wc[(size_t)(128 + k) * 128 + wave * 32 + nt * 16 + m16]);
      }
      wcf[nt][kb] = f;
    }

  const int bt = blockIdx.x;  // 0..63
  int slen[4];
  #pragma unroll
  for (int i = 0; i < 4; ++i) slen[i] = seq_len[bt * 16 + q * 4 + i];

  float h[2][4] = {};  // fp32 hidden state, C-layout

  for (int idx = tid; idx < 16 * 136; idx += 256) { hA[idx] = 0; rhA[idx] = 0; }

  const unsigned short* xg = XGC + (size_t)bt * 200 * 384 * 16;
  auto load_xgc = [&](int t, u32x2* dst) {
    const unsigned short* base = xg + (size_t)t * 384 * 16;
    #pragma unroll
    for (int nt = 0; nt < 4; ++nt)
      dst[nt] = *(const u32x2*)(base + (wave * 64 + nt * 16 + m16) * 16 + q * 4);
    #pragma unroll
    for (int nt = 0; nt < 2; ++nt)
      dst[4 + nt] = *(const u32x2*)(base + (256 + wave * 32 + nt * 16 + m16) * 16 + q * 4);
  };
  u32x2 pf0[6], pf1[6];
  load_xgc(0, pf0);
  load_xgc(1, pf1);
  __syncthreads();

  auto step = [&](int t, u32x2* cur) {
    // ---- P1: gates = sigmoid(XG + h @ Wh_gate) ----
    bf16x8 haf[4];
    #pragma unroll
    for (int kb = 0; kb < 4; ++kb)
      haf[kb] = __builtin_bit_cast(bf16x8, *(const i32x4*)&hA[m16 * 136 + kb * 32 + q * 8]);
    float racc[4][4];
    #pragma unroll
    for (int nt = 0; nt < 4; ++nt) {
      u32x2 p = cur[nt];
      f32x4 acc = { bf2f(p.x & 0xffffu), bf2f(p.x >> 16),
                    bf2f(p.y & 0xffffu), bf2f(p.y >> 16) };
      #pragma unroll
      for (int kb = 0; kb < 4; ++kb)
        acc = __builtin_amdgcn_mfma_f32_16x16x32_bf16(haf[kb], wgf[nt][kb], acc, 0, 0, 0);
      #pragma unroll
      for (int i = 0; i < 4; ++i) racc[nt][i] = sigmoid_fast(acc[i]);
    }
    {
      float* buf = (wave < 2) ? rbuf : ubuf;
      int cbase = (wave & 1) * 64;
      #pragma unroll
      for (int nt = 0; nt < 4; ++nt) {
        int col = cbase + nt * 16 + m16;
        f32x4 v = { racc[nt][0], racc[nt][1], racc[nt][2], racc[nt][3] };
        *(f32x4*)&buf[col * 20 + q * 4] = v;
      }
    }
    __syncthreads();

    // ---- P2: rh = r * h  -> bf16 A-layout ----
    #pragma unroll
    for (int nt = 0; nt < 2; ++nt) {
      int col = wave * 32 + nt * 16 + m16;
      f32x4 rv = *(const f32x4*)&rbuf[col * 20 + q * 4];
      #pragma unroll
      for (int i = 0; i < 4; ++i)
        rhA[(q * 4 + i) * 136 + col] = f2bf(rv[i] * h[nt][i]);
    }
    __syncthreads();

    // ---- P3: c = tanh(XC + rh @ Wh_cand); h update; y store ----
    bf16x8 rhf[4];
    #pragma unroll
    for (int kb = 0; kb < 4; ++kb)
      rhf[kb] = __builtin_bit_cast(bf16x8, *(const i32x4*)&rhA[m16 * 136 + kb * 32 + q * 8]);
    f32x4 cacc[2];
    #pragma unroll
    for (int nt = 0; nt < 2; ++nt) {
      u32x2 p = cur[4 + nt];
      cacc[nt] = (f32x4){ bf2f(p.x & 0xffffu), bf2f(p.x >> 16),
                          bf2f(p.y & 0xffffu), bf2f(p.y >> 16) };
    }
    // cur fully consumed -> prefetch t+2 into the same register buffer
    if (t < 198) load_xgc(t + 2, cur);

    #pragma unroll
    for (int nt = 0; nt < 2; ++nt)
      #pragma unroll
      for (int kb = 0; kb < 4; ++kb)
        cacc[nt] = __builtin_amdgcn_mfma_f32_16x16x32_bf16(rhf[kb], wcf[nt][kb], cacc[nt], 0, 0, 0);

    #pragma unroll
    for (int nt = 0; nt < 2; ++nt) {
      int col = wave * 32 + nt * 16 + m16;
      f32x4 uv = *(const f32x4*)&ubuf[col * 20 + q * 4];
      #pragma unroll
      for (int i = 0; i < 4; ++i) {
        float c  = tanh_fast(cacc[nt][i]);
        float ug = uv[i];
        float hn = ug * (h[nt][i] - c) + c;   // u*h + (1-u)*c
        bool valid = (t < slen[i]);
        float hv = valid ? hn : h[nt][i];
        h[nt][i] = hv;
        Y[((size_t)(bt * 16 + q * 4 + i) * T_SZ + t) * H_SZ + col] = valid ? hn : 0.0f;
        hA[(q * 4 + i) * 136 + col] = f2bf(hv);
      }
    }
    __syncthreads();
  };

  for (int t = 0; t < 200; t += 2) {
    step(t,     pf0);
    step(t + 1, pf1);
  }
}

extern "C" void kernel_launch(void* const* d_in, const int* in_sizes, int n_in,
                              void* d_out, int out_size, void* d_ws, size_t ws_size,
                              hipStream_t stream) {
  const float* X   = (const float*)d_in[0];
  const int*   seq = (const int*)  d_in[1];
  const float* Wg  = (const float*)d_in[2];
  const float* bg  = (const float*)d_in[3];
  const float* Wc  = (const float*)d_in[4];
  const float* bc  = (const float*)d_in[5];
  float* Y = (float*)d_out;
  unsigned short* XGC = (unsigned short*)d_ws;  // 64*200*384*16 bf16 = 157 MB

  hipLaunchKernelGGL(xproj_kernel, dim3(512), dim3(256), 0, stream, X, Wg, bg, Wc, bc, XGC);
  hipLaunchKernelGGL(gru_kernel,   dim3(64),  dim3(256), 0, stream, XGC, seq, Wg, Wc, Y);
}

// Round 2
// 407.839 us; speedup vs baseline: 1.3442x; 1.3442x over previous
//
#include <hip/hip_runtime.h>

// Problem constants: B=1024, T=200, D=128, H=128
#define T_SZ 200
#define H_SZ 128

typedef __attribute__((ext_vector_type(8))) short    bf16x8;
typedef __attribute__((ext_vector_type(4))) float    f32x4;
typedef __attribute__((ext_vector_type(4))) int      i32x4;
typedef __attribute__((ext_vector_type(2))) unsigned u32x2;

__device__ __forceinline__ unsigned short f2bf(float f) {
  unsigned u = __builtin_bit_cast(unsigned, f);
  u += 0x7fffu + ((u >> 16) & 1u);
  return (unsigned short)(u >> 16);
}
__device__ __forceinline__ float bf2f(unsigned us) {
  unsigned v = us << 16;
  return __builtin_bit_cast(float, v);
}
__device__ __forceinline__ float sigmoid_fast(float x) {
  float e = __builtin_amdgcn_exp2f(-1.442695041f * x);
  return __builtin_amdgcn_rcpf(1.0f + e);
}
__device__ __forceinline__ float tanh_fast(float x) {
  float e = __builtin_amdgcn_exp2f(2.885390082f * x);
  return 1.0f - 2.0f * __builtin_amdgcn_rcpf(e + 1.0f);
}
__device__ __forceinline__ f32x4 unpack_bf4(u32x2 p) {
  return (f32x4){ bf2f(p.x & 0xffffu), bf2f(p.x >> 16),
                  bf2f(p.y & 0xffffu), bf2f(p.y >> 16) };
}
// lgkmcnt(0)-only barrier: does NOT drain vmcnt, so global stores and
// register prefetch loads stay in flight across the barrier (unlike
// __syncthreads which emits s_waitcnt vmcnt(0) and kills pipelining).
// 0xc07f = vmcnt(63) expcnt(7) lgkmcnt(0).
__device__ __forceinline__ void ldsbar() {
  __asm__ __volatile__("" ::: "memory");
  __builtin_amdgcn_s_waitcnt(0xc07f);
  __builtin_amdgcn_s_barrier();
  __asm__ __volatile__("" ::: "memory");
}

// ---------------------------------------------------------------------------
// Kernel 1: XGC[bt][t][col(384)][row16] (bf16) = x @ Wx + bias, MFMA C-layout.
// A-tile (16 rows x 128 k) is staged cooperatively through LDS with coalesced
// 512B row reads; double-buffered, register prefetch, 1 lgkm-barrier/tile.
// ---------------------------------------------------------------------------
__global__ __launch_bounds__(256, 2) void xproj_kernel(
    const float* __restrict__ X,   // [B,T,D]
    const float* __restrict__ Wg,  // [256,256]
    const float* __restrict__ bg,  // [256]
    const float* __restrict__ Wc,  // [256,128]
    const float* __restrict__ bc,  // [128]
    unsigned short* __restrict__ XGC)
{
  __shared__ unsigned short Abuf[2][16 * 136];  // bf16, row stride 136 (pad)

  const int tid  = threadIdx.x;
  const int lane = tid & 63;
  const int wave = tid >> 6;   // 0..3
  const int m16  = lane & 15;
  const int q    = lane >> 4;

  // Weight B-fragments in registers (one-time; 4x64B segments per load instr).
  bf16x8 wgf[4][4];  // gate cols [64*wave, +64)
  bf16x8 wcf[2][4];  // cand cols [32*wave, +32)
  float  gbias[4], cbias[2];
  #pragma unroll
  for (int nt = 0; nt < 4; ++nt) {
    int col = wave * 64 + nt * 16 + m16;
    gbias[nt] = bg[col];
    #pragma unroll
    for (int kb = 0; kb < 4; ++kb) {
      bf16x8 f;
      #pragma unroll
      for (int j = 0; j < 8; ++j)
        f[j] = (short)f2bf(Wg[(size_t)(kb * 32 + q * 8 + j) * 256 + col]);
      wgf[nt][kb] = f;
    }
  }
  #pragma unroll
  for (int nt = 0; nt < 2; ++nt) {
    int col = wave * 32 + nt * 16 + m16;
    cbias[nt] = bc[col];
    #pragma unroll
    for (int kb = 0; kb < 4; ++kb) {
      bf16x8 f;
      #pragma unroll
      for (int j = 0; j < 8; ++j)
        f[j] = (short)f2bf(Wc[(size_t)(kb * 32 + q * 8 + j) * 128 + col]);
      wcf[nt][kb] = f;
    }
  }

  const int srow = tid >> 4;        // 0..15 staging row
  const int scol = (tid & 15) * 8;  // staging col (8 floats/thread)
  const int t0   = blockIdx.x * 25; // 512 wgs x 25 tiles = 12800

  auto gload = [&](int tile, f32x4& a, f32x4& b) {
    int bt = tile / 200, t = tile % 200;
    const float* p = X + ((size_t)(bt * 16 + srow) * T_SZ + t) * 128 + scol;
    a = *(const f32x4*)p;
    b = *(const f32x4*)(p + 4);
  };

  f32x4 pa, pb;
  gload(t0, pa, pb);

  for (int it = 0; it < 25; ++it) {
    int tile = t0 + it;
    int bt = tile / 200, t = tile % 200;
    unsigned short* buf = Abuf[it & 1];

    // stage current tile (bf16 pack, one ds_write_b128/thread)
    unsigned d0 = f2bf(pa.x) | ((unsigned)f2bf(pa.y) << 16);
    unsigned d1 = f2bf(pa.z) | ((unsigned)f2bf(pa.w) << 16);
    unsigned d2 = f2bf(pb.x) | ((unsigned)f2bf(pb.y) << 16);
    unsigned d3 = f2bf(pb.z) | ((unsigned)f2bf(pb.w) << 16);
    i32x4 pk = { (int)d0, (int)d1, (int)d2, (int)d3 };
    *(i32x4*)&buf[srow * 136 + scol] = pk;

    ldsbar();  // staging visible; vmcnt (stores/prefetch) stays in flight

    if (it < 24) gload(tile + 1, pa, pb);  // prefetch next tile

    bf16x8 af[4];
    #pragma unroll
    for (int kb = 0; kb < 4; ++kb)
      af[kb] = __builtin_bit_cast(bf16x8, *(const i32x4*)&buf[m16 * 136 + kb * 32 + q * 8]);

    unsigned short* outbase = XGC + ((size_t)bt * 200 + t) * 384 * 16;
    #pragma unroll
    for (int nt = 0; nt < 4; ++nt) {
      f32x4 acc = { gbias[nt], gbias[nt], gbias[nt], gbias[nt] };
      #pragma unroll
      for (int kb = 0; kb < 4; ++kb)
        acc = __builtin_amdgcn_mfma_f32_16x16x32_bf16(af[kb], wgf[nt][kb], acc, 0, 0, 0);
      int col = wave * 64 + nt * 16 + m16;
      unsigned h0 = f2bf(acc[0]), h1 = f2bf(acc[1]), h2 = f2bf(acc[2]), h3 = f2bf(acc[3]);
      u32x2 pko = { h0 | (h1 << 16), h2 | (h3 << 16) };
      *(u32x2*)(outbase + col * 16 + q * 4) = pko;
    }
    #pragma unroll
    for (int nt = 0; nt < 2; ++nt) {
      f32x4 acc = { cbias[nt], cbias[nt], cbias[nt], cbias[nt] };
      #pragma unroll
      for (int kb = 0; kb < 4; ++kb)
        acc = __builtin_amdgcn_mfma_f32_16x16x32_bf16(af[kb], wcf[nt][kb], acc, 0, 0, 0);
      int col = 256 + wave * 32 + nt * 16 + m16;
      unsigned h0 = f2bf(acc[0]), h1 = f2bf(acc[1]), h2 = f2bf(acc[2]), h3 = f2bf(acc[3]);
      u32x2 pko = { h0 | (h1 << 16), h2 | (h3 << 16) };
      *(u32x2*)(outbase + col * 16 + q * 4) = pko;
    }
    // no second barrier: double buffer, prior readers drained at next ldsbar
  }
}

// ---------------------------------------------------------------------------
// Kernel 2: GRU recurrence. 64 wgs x 512 threads (8 waves = 2/SIMD).
// Wave w: gate cols [32w,+32) (w<4 -> r, w>=4 -> u); cand/h cols [16w,+16).
// 2 lgkm-barriers/step; rh transpose folded into P1 via fp32 hF in LDS.
// ---------------------------------------------------------------------------
__global__ __launch_bounds__(512, 1) void gru_kernel(
    const unsigned short* __restrict__ XGC,
    const int*   __restrict__ seq_len,
    const float* __restrict__ Wg,   // [256,256] rows 128.. = h-part
    const float* __restrict__ Wc,   // [256,128] rows 128.. = h-part
    float* __restrict__ Y)          // [B,T,H]
{
  __shared__ unsigned short hA[16 * 136];   // h bf16, A-layout [row][k]
  __shared__ unsigned short rhA[16 * 136];  // r*h bf16, A-layout
  __shared__ float hF[16 * 132];            // h fp32, [row][col]
  __shared__ float ubuf[128 * 20];          // u fp32, [col][row]

  const int tid  = threadIdx.x;
  const int lane = tid & 63;
  const int w    = tid >> 6;   // 0..7
  const int m16  = lane & 15;
  const int q    = lane >> 4;

  // Recurrent-weight B-fragments (h-part rows 128..255).
  bf16x8 wgf[2][4], wcf[4];
  #pragma unroll
  for (int nt = 0; nt < 2; ++nt)
    #pragma unroll
    for (int kb = 0; kb < 4; ++kb) {
      bf16x8 f;
      #pragma unroll
      for (int j = 0; j < 8; ++j)
        f[j] = (short)f2bf(Wg[(size_t)(128 + kb * 32 + q * 8 + j) * 256 + w * 32 + nt * 16 + m16]);
      wgf[nt][kb] = f;
    }
  const int colc = w * 16 + m16;  // this wave's cand/h column
  #pragma unroll
  for (int kb = 0; kb < 4; ++kb) {
    bf16x8 f;
    #pragma unroll
    for (int j = 0; j < 8; ++j)
      f[j] = (short)f2bf(Wc[(size_t)(128 + kb * 32 + q * 8 + j) * 128 + colc]);
    wcf[kb] = f;
  }

  const int bt = blockIdx.x;  // 0..63
  int slen[4];
  #pragma unroll
  for (int i = 0; i < 4; ++i) slen[i] = seq_len[bt * 16 + q * 4 + i];

  float h[4] = {0.f, 0.f, 0.f, 0.f};

  for (int idx = tid; idx < 16 * 136; idx += 512) hA[idx] = 0;
  for (int idx = tid; idx < 16 * 132; idx += 512) hF[idx] = 0.f;

  const unsigned short* xg = XGC + (size_t)bt * 200 * 384 * 16;
  auto load_xgc = [&](int t, u32x2* d) {
    const unsigned short* base = xg + (size_t)t * 384 * 16;
    d[0] = *(const u32x2*)(base + (w * 32 + m16) * 16 + q * 4);
    d[1] = *(const u32x2*)(base + (w * 32 + 16 + m16) * 16 + q * 4);
    d[2] = *(const u32x2*)(base + (256 + colc) * 16 + q * 4);
  };
  u32x2 pf0[3], pf1[3];
  load_xgc(0, pf0);
  load_xgc(1, pf1);
  ldsbar();  // covers hA/hF zero-init

  auto step = [&](int t, u32x2* cur) {
    // ---- P1: gates ----
    bf16x8 haf[4];
    #pragma unroll
    for (int kb = 0; kb < 4; ++kb)
      haf[kb] = __builtin_bit_cast(bf16x8, *(const i32x4*)&hA[m16 * 136 + kb * 32 + q * 8]);

    // consume cand XC now so `cur` can be reused for the t+2 prefetch
    f32x4 cacc = unpack_bf4(cur[2]);

    float racc[2][4];
    #pragma unroll
    for (int nt = 0; nt < 2; ++nt) {
      f32x4 acc = unpack_bf4(cur[nt]);
      #pragma unroll
      for (int kb = 0; kb < 4; ++kb)
        acc = __builtin_amdgcn_mfma_f32_16x16x32_bf16(haf[kb], wgf[nt][kb], acc, 0, 0, 0);
      #pragma unroll
      for (int i = 0; i < 4; ++i) racc[nt][i] = sigmoid_fast(acc[i]);
    }

    if (t < 198) load_xgc(t + 2, cur);  // depth-2 prefetch, survives lgkm barriers

    if (w < 4) {
      // r-waves: rh = r * h (fp32) -> bf16 A-layout, directly
      #pragma unroll
      for (int nt = 0; nt < 2; ++nt) {
        int col = w * 32 + nt * 16 + m16;
        #pragma unroll
        for (int i = 0; i < 4; ++i) {
          int row = q * 4 + i;
          float hf = hF[row * 132 + col];
          rhA[row * 136 + col] = f2bf(racc[nt][i] * hf);
        }
      }
    } else {
      // u-waves: publish u
      #pragma unroll
      for (int nt = 0; nt < 2; ++nt) {
        int colu = (w - 4) * 32 + nt * 16 + m16;
        f32x4 v = { racc[nt][0], racc[nt][1], racc[nt][2], racc[nt][3] };
        *(f32x4*)&ubuf[colu * 20 + q * 4] = v;
      }
    }
    ldsbar();

    // ---- P2: candidate + h update ----
    bf16x8 rhf[4];
    #pragma unroll
    for (int kb = 0; kb < 4; ++kb)
      rhf[kb] = __builtin_bit_cast(bf16x8, *(const i32x4*)&rhA[m16 * 136 + kb * 32 + q * 8]);
    #pragma unroll
    for (int kb = 0; kb < 4; ++kb)
      cacc = __builtin_amdgcn_mfma_f32_16x16x32_bf16(rhf[kb], wcf[kb], cacc, 0, 0, 0);

    f32x4 uv = *(const f32x4*)&ubuf[colc * 20 + q * 4];
    #pragma unroll
    for (int i = 0; i < 4; ++i) {
      float c  = tanh_fast(cacc[i]);
      float hn = uv[i] * (h[i] - c) + c;   // u*h + (1-u)*c
      bool valid = (t < slen[i]);
      float hv = valid ? hn : h[i];
      h[i] = hv;
      int row = q * 4 + i;
      Y[((size_t)(bt * 16 + row) * T_SZ + t) * H_SZ + colc] = valid ? hn : 0.0f;
      hA[row * 136 + colc] = f2bf(hv);
      hF[row * 132 + colc] = hv;
    }
    ldsbar();
  };

  for (int t = 0; t < 200; t += 2) {
    step(t,     pf0);
    step(t + 1, pf1);
  }
}

extern "C" void kernel_launch(void* const* d_in, const int* in_sizes, int n_in,
                              void* d_out, int out_size, void* d_ws, size_t ws_size,
                              hipStream_t stream) {
  const float* X   = (const float*)d_in[0];
  const int*   seq = (const int*)  d_in[1];
  const float* Wg  = (const float*)d_in[2];
  const float* bg  = (const float*)d_in[3];
  const float* Wc  = (const float*)d_in[4];
  const float* bc  = (const float*)d_in[5];
  float* Y = (float*)d_out;
  unsigned short* XGC = (unsigned short*)d_ws;  // 64*200*384*16 bf16 = 157 MB

  hipLaunchKernelGGL(xproj_kernel, dim3(512), dim3(256), 0, stream, X, Wg, bg, Wc, bc, XGC);
  hipLaunchKernelGGL(gru_kernel,   dim3(64),  dim3(512), 0, stream, XGC, seq, Wg, Wc, Y);
}